// Round 6
// baseline (136.570 us; speedup 1.0000x reference)
//
#include <hip/hip_runtime.h>
#include <hip/hip_fp16.h>

// FLAME mesh SE3 extraction: T=128 frames, V=5023 vertices, K=16 neighbors.
// R6: occupancy attack. R4/R5 falsified LDS-instr-count and block-independence
// theories (both ~0 delta). All prior rounds topped out at 16 waves/CU.
// Now: 1024-thr blocks, 80,368 B fp16 LDS -> 2 blocks/CU co-resident ->
// 32 waves/CU, forced by __launch_bounds__(1024, 8) (VGPR <= 64).
// Register diet: 16-bit mask word instead of float mk[16]; neighbor indices
// loaded per group-of-4 (int4) and consumed immediately; self vertex from LDS
// (fp16 translation err ~2e-4 << 2e-2 threshold). Newton 8 -> 6 iters.
// Frame mapping: t = bid & 127, 4 blocks/frame, 128%8==0 -> all 4 on one XCD.

namespace {
constexpr int T_FRAMES = 128;
constexpr int V_NUM    = 5023;
constexpr int K_NB     = 16;
constexpr int SLAB     = V_NUM * 3;            // floats per frame per array
constexpr int VPB      = 1256;                 // vertices per block (4*1256 >= 5023)
constexpr int LDS_BYTES = V_NUM * 16;          // 80,368 B -> 2 blocks/CU
}

union VRec {
    uint4   u;
    __half2 h[4];   // h[0]=(cx,cy) h[1]=(cz,dx) h[2]=(dy,dz) h[3]=pad
};

__global__ __launch_bounds__(1024, 8)
void se3_extract_kernel(const float* __restrict__ cano,
                        const float* __restrict__ defo,
                        const int*   __restrict__ nbr,
                        const unsigned char* __restrict__ mask_raw,
                        float* __restrict__ out) {
    extern __shared__ uint4 ldsv[];   // [V_NUM] packed fp16 cano+defo

    const int bid  = blockIdx.x;
    const int t    = bid & 127;       // frame
    const int quar = bid >> 7;        // 0..3 -> vertex quarter
    const int tid  = threadIdx.x;

    // ---- per-wave mask dtype detect from first 256 B (L2-broadcast).
    //      bool: odd bytes ==1 (~96% lanes); f32: top byte 0x3F (~80%);
    //      int32: neither. flag: 0=int32, 1=bool, 2=f32. ----
    int mflag;
    {
        const unsigned w = reinterpret_cast<const unsigned*>(mask_raw)[tid & 63];
        const bool isb = ((((w >> 8) & 0xffu) == 1u) | (((w >> 24) & 0xffu) == 1u));
        const bool isf = ((w >> 24) == 0x3fu);
        const unsigned long long mb = __ballot(isb);
        const unsigned long long mf = __ballot(isf);
        mflag = 0;
        if (__popcll(mb) > 16)      mflag = 1;
        else if (__popcll(mf) > 16) mflag = 2;
    }

    // ---- stage full frame into LDS as packed fp16 records ----
    {
        const float* __restrict__ cfp = cano + (size_t)t * SLAB;
        const float* __restrict__ dfp = defo + (size_t)t * SLAB;
        for (int i = tid; i < V_NUM; i += 1024) {
            const float* cp = cfp + i * 3;
            const float* dp = dfp + i * 3;
            VRec r;
            r.h[0] = __floats2half2_rn(cp[0], cp[1]);
            r.h[1] = __floats2half2_rn(cp[2], dp[0]);
            r.h[2] = __floats2half2_rn(dp[1], dp[2]);
            r.h[3] = __floats2half2_rn(0.0f, 0.0f);
            ldsv[i] = r.u;
        }
    }
    __syncthreads();

    const int vbeg = quar * VPB;
    const int vend = (vbeg + VPB < V_NUM) ? vbeg + VPB : V_NUM;

    for (int v = vbeg + tid; v < vend; v += 1024) {
        // ---- mask -> 16-bit word (bit k = slot k valid), low reg pressure ----
        unsigned mbits = 0;
        if (mflag == 1) {
            const uint4 mw = *reinterpret_cast<const uint4*>(mask_raw + (size_t)v * K_NB);
            const unsigned w[4] = {mw.x, mw.y, mw.z, mw.w};
            #pragma unroll
            for (int j = 0; j < 4; ++j) {
                mbits |= (((w[j]       ) & 0xffu) != 0u ? 1u : 0u) << (j*4+0);
                mbits |= (((w[j] >> 8  ) & 0xffu) != 0u ? 1u : 0u) << (j*4+1);
                mbits |= (((w[j] >> 16 ) & 0xffu) != 0u ? 1u : 0u) << (j*4+2);
                mbits |= (((w[j] >> 24 ) & 0xffu) != 0u ? 1u : 0u) << (j*4+3);
            }
        } else if (mflag == 0) {
            const int* mp = reinterpret_cast<const int*>(mask_raw) + (size_t)v * K_NB;
            #pragma unroll
            for (int k = 0; k < K_NB; ++k) mbits |= (mp[k] ? 1u : 0u) << k;
        } else {
            const float* mp = reinterpret_cast<const float*>(mask_raw) + (size_t)v * K_NB;
            #pragma unroll
            for (int k = 0; k < K_NB; ++k) mbits |= ((mp[k] != 0.0f) ? 1u : 0u) << k;
        }

        // self vertex from LDS (fp16)
        float cvx, cvy, cvz, dvx, dvy, dvz;
        {
            VRec r; r.u = ldsv[v];
            const float2 f0 = __half22float2(r.h[0]);
            const float2 f1 = __half22float2(r.h[1]);
            const float2 f2 = __half22float2(r.h[2]);
            cvx = f0.x; cvy = f0.y; cvz = f1.x;
            dvx = f1.y; dvy = f2.x; dvz = f2.y;
        }

        // ---- covariance A[i][j] = sum_k pc_i*qc_j; neighbors in groups of 4 ----
        float a00=0.f,a01=0.f,a02=0.f,a10=0.f,a11=0.f,a12=0.f,a20=0.f,a21=0.f,a22=0.f;
        const int4* __restrict__ nb4 = reinterpret_cast<const int4*>(nbr + (size_t)v * K_NB);
        #pragma unroll
        for (int g = 0; g < 4; ++g) {
            const int4 nq = nb4[g];
            const int ni[4] = {nq.x, nq.y, nq.z, nq.w};
            #pragma unroll
            for (int j = 0; j < 4; ++j) {
                VRec r; r.u = ldsv[ni[j]];
                const float m = ((mbits >> (g*4+j)) & 1u) ? 1.0f : 0.0f;
                const float2 f0 = __half22float2(r.h[0]);   // cx, cy
                const float2 f1 = __half22float2(r.h[1]);   // cz, dx
                const float2 f2 = __half22float2(r.h[2]);   // dy, dz
                const float px = fmaf(f0.x, m, -cvx);
                const float py = fmaf(f0.y, m, -cvy);
                const float pz = fmaf(f1.x, m, -cvz);
                const float qx = fmaf(f1.y, m, -dvx);
                const float qy = fmaf(f2.x, m, -dvy);
                const float qz = fmaf(f2.y, m, -dvz);
                a00 = fmaf(px,qx,a00); a01 = fmaf(px,qy,a01); a02 = fmaf(px,qz,a02);
                a10 = fmaf(py,qx,a10); a11 = fmaf(py,qy,a11); a12 = fmaf(py,qz,a12);
                a20 = fmaf(pz,qx,a20); a21 = fmaf(pz,qy,a21); a22 = fmaf(pz,qz,a22);
            }
        }

        // ---- R = polar(A^T): scale once by sign*|det|^(-1/3) (det(X0)=+1),
        //      then pure Newton X <- 0.5*X + 0.5*cof(X)/det(X). ----
        float x00=a00, x01=a10, x02=a20;
        float x10=a01, x11=a11, x12=a21;
        float x20=a02, x21=a12, x22=a22;
        {
            const float d0 = x00*(x11*x22 - x12*x21)
                           - x01*(x10*x22 - x12*x20)
                           + x02*(x10*x21 - x11*x20);
            const float ad = fmaxf(fabsf(d0), 1e-30f);
            float mu = __builtin_amdgcn_exp2f(-0.3333333333f *
                                              __builtin_amdgcn_logf(ad));
            if (d0 < 0.0f) mu = -mu;
            x00*=mu; x01*=mu; x02*=mu;
            x10*=mu; x11*=mu; x12*=mu;
            x20*=mu; x21*=mu; x22*=mu;
        }
        #pragma unroll
        for (int it = 0; it < 6; ++it) {
            const float c00 = x11*x22 - x12*x21;
            const float c01 = x12*x20 - x10*x22;
            const float c02 = x10*x21 - x11*x20;
            const float c10 = x02*x21 - x01*x22;
            const float c11 = x00*x22 - x02*x20;
            const float c12 = x01*x20 - x00*x21;
            const float c20 = x01*x12 - x02*x11;
            const float c21 = x02*x10 - x00*x12;
            const float c22 = x00*x11 - x01*x10;
            const float det = x00*c00 + x01*c01 + x02*c02;   // ~ +1
            const float r   = 0.5f * __builtin_amdgcn_rcpf(det);
            x00 = fmaf(0.5f, x00, r*c00); x01 = fmaf(0.5f, x01, r*c01); x02 = fmaf(0.5f, x02, r*c02);
            x10 = fmaf(0.5f, x10, r*c10); x11 = fmaf(0.5f, x11, r*c11); x12 = fmaf(0.5f, x12, r*c12);
            x20 = fmaf(0.5f, x20, r*c20); x21 = fmaf(0.5f, x21, r*c21); x22 = fmaf(0.5f, x22, r*c22);
        }

        // ---- quaternion, replicating reference 4-candidate argmax ----
        const float qa0 = sqrtf(fmaxf(1.0f + x00 + x11 + x22, 0.0f));
        const float qa1 = sqrtf(fmaxf(1.0f + x00 - x11 - x22, 0.0f));
        const float qa2 = sqrtf(fmaxf(1.0f - x00 + x11 - x22, 0.0f));
        const float qa3 = sqrtf(fmaxf(1.0f - x00 - x11 + x22, 0.0f));

        int best = 0; float bq = qa0;           // first-max tie-break = jnp.argmax
        if (qa1 > bq) { best = 1; bq = qa1; }
        if (qa2 > bq) { best = 2; bq = qa2; }
        if (qa3 > bq) { best = 3; bq = qa3; }

        float r0, r1, r2, r3;
        if      (best == 0) { r0 = qa0*qa0; r1 = x21-x12; r2 = x02-x20; r3 = x10-x01; }
        else if (best == 1) { r0 = x21-x12; r1 = qa1*qa1; r2 = x01+x10; r3 = x02+x20; }
        else if (best == 2) { r0 = x02-x20; r1 = x10+x01; r2 = qa2*qa2; r3 = x12+x21; }
        else                { r0 = x10-x01; r1 = x20+x02; r2 = x21+x12; r3 = qa3*qa3; }
        const float qi = __builtin_amdgcn_rcpf(2.0f * fmaxf(bq, 0.1f));

        const size_t base_q = ((size_t)t * V_NUM + v) * 4;
        float4 qout;
        qout.x = r0 * qi; qout.y = r1 * qi; qout.z = r2 * qi; qout.w = r3 * qi;
        *reinterpret_cast<float4*>(out + base_q) = qout;

        const size_t base_t = (size_t)T_FRAMES * V_NUM * 4 + ((size_t)t * V_NUM + v) * 3;
        out[base_t+0] = dvx - cvx;
        out[base_t+1] = dvy - cvy;
        out[base_t+2] = dvz - cvz;
    }
}

extern "C" void kernel_launch(void* const* d_in, const int* in_sizes, int n_in,
                              void* d_out, int out_size, void* d_ws, size_t ws_size,
                              hipStream_t stream) {
    const float* cano = (const float*)d_in[0];
    const float* defo = (const float*)d_in[1];
    const int*   nbr  = (const int*)d_in[2];
    const unsigned char* mask = (const unsigned char*)d_in[3];
    float* out = (float*)d_out;

    // Allow ~78.5 KB dynamic LDS (host-side config, idempotent).
    static bool attr_set = false;
    if (!attr_set) {
        (void)hipFuncSetAttribute((const void*)se3_extract_kernel,
                                  hipFuncAttributeMaxDynamicSharedMemorySize,
                                  LDS_BYTES);
        attr_set = true;
    }

    // 4 blocks per frame (vertex quarters); t = bid & 127; 2 blocks/CU,
    // 32 waves/CU (VGPR capped at 64 by __launch_bounds__(1024, 8)).
    se3_extract_kernel<<<512, 1024, LDS_BYTES, stream>>>(cano, defo, nbr, mask, out);
}

// Round 8
// 91.859 us; speedup vs baseline: 1.4867x; 1.4867x over previous
//
#include <hip/hip_runtime.h>
#include <hip/hip_fp16.h>

// FLAME mesh SE3 extraction: T=128 frames, V=5023 vertices, K=16 neighbors.
// R8: correctness recovery. R7's packed-fp16 covariance failed (absmax 3.1e-2
// == fp16 ulp at sum magnitude ~30: fp16 ACCUMULATION is fatal; fp16 inputs
// are fine -- R5/R6 passed at 3.9e-3). Revert to f32 covariance from fp16 LDS
// records; Newton 6 iters (R6-proven). New exact trims: quaternion candidate
// argmax over SQUARES (sqrt only for the winner; selection identical since
// sqrt is monotone and clip(s,0) keeps order; reference's diag entry is
// sqrt(s)^2 ~= s). Config: 512 blocks x 512 thr, 80,368 B LDS, 2 blocks/CU,
// VGPR<=128 (R6's 64-cap spilled -> 171 MB scratch writes).

namespace {
constexpr int T_FRAMES = 128;
constexpr int V_NUM    = 5023;
constexpr int K_NB     = 16;
constexpr int SLAB     = V_NUM * 3;            // floats per frame per array
constexpr int VPB      = 1256;                 // vertices per block (4*1256 >= 5023)
constexpr int LDS_BYTES = V_NUM * 16;          // 80,368 B -> 2 blocks/CU
}

union VRec {
    uint4   u;
    __half2 h[4];   // h[0]=(cx,cy) h[1]=(cz,dx) h[2]=(dy,dz) h[3]=pad
};

__global__ __launch_bounds__(512, 4)
void se3_extract_kernel(const float* __restrict__ cano,
                        const float* __restrict__ defo,
                        const int*   __restrict__ nbr,
                        const unsigned char* __restrict__ mask_raw,
                        float* __restrict__ out) {
    extern __shared__ uint4 ldsv[];   // [V_NUM] packed fp16 cano+defo

    const int bid  = blockIdx.x;
    const int t    = bid & 127;       // frame
    const int quar = bid >> 7;        // 0..3 -> vertex quarter
    const int tid  = threadIdx.x;

    // ---- per-wave mask dtype detect from first 256 B (L2-broadcast).
    //      flag: 0=int32, 1=bool, 2=f32. ----
    int mflag;
    {
        const unsigned w = reinterpret_cast<const unsigned*>(mask_raw)[tid & 63];
        const bool isb = ((((w >> 8) & 0xffu) == 1u) | (((w >> 24) & 0xffu) == 1u));
        const bool isf = ((w >> 24) == 0x3fu);
        const unsigned long long mb = __ballot(isb);
        const unsigned long long mf = __ballot(isf);
        mflag = 0;
        if (__popcll(mb) > 16)      mflag = 1;
        else if (__popcll(mf) > 16) mflag = 2;
    }

    // ---- stage full frame into LDS as packed fp16 records ----
    {
        const float* __restrict__ cfp = cano + (size_t)t * SLAB;
        const float* __restrict__ dfp = defo + (size_t)t * SLAB;
        for (int i = tid; i < V_NUM; i += 512) {
            const float* cp = cfp + i * 3;
            const float* dp = dfp + i * 3;
            VRec r;
            r.h[0] = __floats2half2_rn(cp[0], cp[1]);
            r.h[1] = __floats2half2_rn(cp[2], dp[0]);
            r.h[2] = __floats2half2_rn(dp[1], dp[2]);
            r.h[3] = __floats2half2_rn(0.0f, 0.0f);
            ldsv[i] = r.u;
        }
    }
    __syncthreads();

    const int vbeg = quar * VPB;
    const int vend = (vbeg + VPB < V_NUM) ? vbeg + VPB : V_NUM;

    for (int v = vbeg + tid; v < vend; v += 512) {
        // ---- mask -> 16-bit word (bit k = slot k valid) ----
        unsigned mbits = 0;
        if (mflag == 1) {
            const uint4 mw = *reinterpret_cast<const uint4*>(mask_raw + (size_t)v * K_NB);
            const unsigned w[4] = {mw.x, mw.y, mw.z, mw.w};
            #pragma unroll
            for (int j = 0; j < 4; ++j) {
                mbits |= (((w[j]       ) & 0xffu) != 0u ? 1u : 0u) << (j*4+0);
                mbits |= (((w[j] >> 8  ) & 0xffu) != 0u ? 1u : 0u) << (j*4+1);
                mbits |= (((w[j] >> 16 ) & 0xffu) != 0u ? 1u : 0u) << (j*4+2);
                mbits |= (((w[j] >> 24 ) & 0xffu) != 0u ? 1u : 0u) << (j*4+3);
            }
        } else if (mflag == 0) {
            const int* mp = reinterpret_cast<const int*>(mask_raw) + (size_t)v * K_NB;
            #pragma unroll
            for (int k = 0; k < K_NB; ++k) mbits |= (mp[k] ? 1u : 0u) << k;
        } else {
            const float* mp = reinterpret_cast<const float*>(mask_raw) + (size_t)v * K_NB;
            #pragma unroll
            for (int k = 0; k < K_NB; ++k) mbits |= ((mp[k] != 0.0f) ? 1u : 0u) << k;
        }

        // self vertex from LDS (fp16) -> f32
        float cvx, cvy, cvz, dvx, dvy, dvz;
        {
            VRec r; r.u = ldsv[v];
            const float2 f0 = __half22float2(r.h[0]);
            const float2 f1 = __half22float2(r.h[1]);
            const float2 f2 = __half22float2(r.h[2]);
            cvx = f0.x; cvy = f0.y; cvz = f1.x;
            dvx = f1.y; dvy = f2.x; dvz = f2.y;
        }

        // ---- covariance A[i][j] = sum_k pc_i*qc_j; f32 math, fp16 inputs ----
        float a00=0.f,a01=0.f,a02=0.f,a10=0.f,a11=0.f,a12=0.f,a20=0.f,a21=0.f,a22=0.f;
        const int4* __restrict__ nb4 = reinterpret_cast<const int4*>(nbr + (size_t)v * K_NB);
        #pragma unroll
        for (int g = 0; g < 4; ++g) {
            const int4 nq = nb4[g];
            const int ni[4] = {nq.x, nq.y, nq.z, nq.w};
            #pragma unroll
            for (int j = 0; j < 4; ++j) {
                VRec r; r.u = ldsv[ni[j]];
                const float m = ((mbits >> (g*4+j)) & 1u) ? 1.0f : 0.0f;
                const float2 f0 = __half22float2(r.h[0]);   // cx, cy
                const float2 f1 = __half22float2(r.h[1]);   // cz, dx
                const float2 f2 = __half22float2(r.h[2]);   // dy, dz
                const float px = fmaf(f0.x, m, -cvx);
                const float py = fmaf(f0.y, m, -cvy);
                const float pz = fmaf(f1.x, m, -cvz);
                const float qx = fmaf(f1.y, m, -dvx);
                const float qy = fmaf(f2.x, m, -dvy);
                const float qz = fmaf(f2.y, m, -dvz);
                a00 = fmaf(px,qx,a00); a01 = fmaf(px,qy,a01); a02 = fmaf(px,qz,a02);
                a10 = fmaf(py,qx,a10); a11 = fmaf(py,qy,a11); a12 = fmaf(py,qz,a12);
                a20 = fmaf(pz,qx,a20); a21 = fmaf(pz,qy,a21); a22 = fmaf(pz,qz,a22);
            }
        }

        // ---- R = polar(A^T): scale once by sign*|det|^(-1/3) (det(X0)=+1),
        //      then pure Newton X <- 0.5*X + 0.5*cof(X)/det(X), 6 iters. ----
        float x00=a00, x01=a10, x02=a20;
        float x10=a01, x11=a11, x12=a21;
        float x20=a02, x21=a12, x22=a22;
        {
            const float d0 = x00*(x11*x22 - x12*x21)
                           - x01*(x10*x22 - x12*x20)
                           + x02*(x10*x21 - x11*x20);
            const float ad = fmaxf(fabsf(d0), 1e-30f);
            float mu = __builtin_amdgcn_exp2f(-0.3333333333f *
                                              __builtin_amdgcn_logf(ad));
            if (d0 < 0.0f) mu = -mu;
            x00*=mu; x01*=mu; x02*=mu;
            x10*=mu; x11*=mu; x12*=mu;
            x20*=mu; x21*=mu; x22*=mu;
        }
        #pragma unroll
        for (int it = 0; it < 6; ++it) {
            const float c00 = x11*x22 - x12*x21;
            const float c01 = x12*x20 - x10*x22;
            const float c02 = x10*x21 - x11*x20;
            const float c10 = x02*x21 - x01*x22;
            const float c11 = x00*x22 - x02*x20;
            const float c12 = x01*x20 - x00*x21;
            const float c20 = x01*x12 - x02*x11;
            const float c21 = x02*x10 - x00*x12;
            const float c22 = x00*x11 - x01*x10;
            const float det = x00*c00 + x01*c01 + x02*c02;   // ~ +1
            const float r   = 0.5f * __builtin_amdgcn_rcpf(det);
            x00 = fmaf(0.5f, x00, r*c00); x01 = fmaf(0.5f, x01, r*c01); x02 = fmaf(0.5f, x02, r*c02);
            x10 = fmaf(0.5f, x10, r*c10); x11 = fmaf(0.5f, x11, r*c11); x12 = fmaf(0.5f, x12, r*c12);
            x20 = fmaf(0.5f, x20, r*c20); x21 = fmaf(0.5f, x21, r*c21); x22 = fmaf(0.5f, x22, r*c22);
        }

        // ---- quaternion: argmax over candidate SQUARES (monotone == reference
        //      argmax over sqrt), single sqrt for the winner ----
        const float s0 = fmaxf(1.0f + x00 + x11 + x22, 0.0f);
        const float s1 = fmaxf(1.0f + x00 - x11 - x22, 0.0f);
        const float s2 = fmaxf(1.0f - x00 + x11 - x22, 0.0f);
        const float s3 = fmaxf(1.0f - x00 - x11 + x22, 0.0f);

        int best = 0; float bs = s0;            // first-max tie-break = jnp.argmax
        if (s1 > bs) { best = 1; bs = s1; }
        if (s2 > bs) { best = 2; bs = s2; }
        if (s3 > bs) { best = 3; bs = s3; }
        const float bq = sqrtf(bs);

        float r0, r1, r2, r3;
        if      (best == 0) { r0 = bs;      r1 = x21-x12; r2 = x02-x20; r3 = x10-x01; }
        else if (best == 1) { r0 = x21-x12; r1 = bs;      r2 = x01+x10; r3 = x02+x20; }
        else if (best == 2) { r0 = x02-x20; r1 = x10+x01; r2 = bs;      r3 = x12+x21; }
        else                { r0 = x10-x01; r1 = x20+x02; r2 = x21+x12; r3 = bs;      }
        const float qi = __builtin_amdgcn_rcpf(2.0f * fmaxf(bq, 0.1f));

        const size_t base_q = ((size_t)t * V_NUM + v) * 4;
        float4 qout;
        qout.x = r0 * qi; qout.y = r1 * qi; qout.z = r2 * qi; qout.w = r3 * qi;
        *reinterpret_cast<float4*>(out + base_q) = qout;

        const size_t base_t = (size_t)T_FRAMES * V_NUM * 4 + ((size_t)t * V_NUM + v) * 3;
        out[base_t+0] = dvx - cvx;
        out[base_t+1] = dvy - cvy;
        out[base_t+2] = dvz - cvz;
    }
}

extern "C" void kernel_launch(void* const* d_in, const int* in_sizes, int n_in,
                              void* d_out, int out_size, void* d_ws, size_t ws_size,
                              hipStream_t stream) {
    const float* cano = (const float*)d_in[0];
    const float* defo = (const float*)d_in[1];
    const int*   nbr  = (const int*)d_in[2];
    const unsigned char* mask = (const unsigned char*)d_in[3];
    float* out = (float*)d_out;

    // Allow ~78.5 KB dynamic LDS (host-side config, idempotent).
    static bool attr_set = false;
    if (!attr_set) {
        (void)hipFuncSetAttribute((const void*)se3_extract_kernel,
                                  hipFuncAttributeMaxDynamicSharedMemorySize,
                                  LDS_BYTES);
        attr_set = true;
    }

    // 4 blocks per frame (vertex quarters); t = bid & 127; 2 blocks/CU,
    // 16 waves/CU, VGPR <= 128 (no spill).
    se3_extract_kernel<<<512, 512, LDS_BYTES, stream>>>(cano, defo, nbr, mask, out);
}